// Round 9
// baseline (190.216 us; speedup 1.0000x reference)
//
#include <hip/hip_runtime.h>
#include <cmath>

typedef unsigned short u16;
typedef unsigned int u32;
typedef __bf16 bf16x8 __attribute__((ext_vector_type(8)));
typedef float f32x4 __attribute__((ext_vector_type(4)));

#define D_MODEL 1024
#define NHEAD 16
#define HD 64
#define SEQ 2048
#define BATCH 2
#define M_TOK 4096      // BATCH*SEQ
#define N_QKV 3072

// Q epilogue scale: 0.125 (1/sqrt(64)) * log2(e), folded so softmax is a bare exp2
#define Q_SCALE 0.18033688011112042f

// float -> bf16 round-to-nearest-even (matches HW cvt)
__device__ __forceinline__ u16 f2bf(float f) {
    u32 u = __float_as_uint(f);
    u32 r = (u + 0x7fffu + ((u >> 16) & 1u)) >> 16;
    return (u16)r;
}

__device__ __forceinline__ float bf2f(u16 v) {
    return __uint_as_float(((u32)v) << 16);
}

// HW exp2: single v_exp_f32 (R6->R7 win: -17us, OCML expansion removed)
__device__ __forceinline__ float fast_exp2(float x) {
#if __has_builtin(__builtin_amdgcn_exp2f)
    return __builtin_amdgcn_exp2f(x);
#else
    return __exp2f(x);
#endif
}

// pack two fp32 -> two bf16 in one b32 (a in low half)
__device__ __forceinline__ u32 pack_bf(float a, float b) {
#if __has_builtin(__builtin_amdgcn_cvt_pk_bf16_f32)
    typedef __bf16 bf16x2_t __attribute__((ext_vector_type(2)));
    union { bf16x2_t v; u32 u; } c;
    c.v = __builtin_amdgcn_cvt_pk_bf16_f32(a, b);
    return c.u;
#else
    u32 ua = __float_as_uint(a) + 0x8000u;
    u32 ub = __float_as_uint(b) + 0x8000u;
    return __builtin_amdgcn_perm(ub, ua, 0x07060302u);
#endif
}

__device__ __forceinline__ bf16x8 ld_bf8(const u16* p) {
    return *(const bf16x8*)p;
}

__device__ __forceinline__ bf16x8 as_bf8(int4 v) {
    union { int4 i; bf16x8 b; } u; u.i = v; return u.b;
}

__device__ __forceinline__ f32x4 mfma16(bf16x8 a, bf16x8 b, f32x4 c) {
    return __builtin_amdgcn_mfma_f32_16x16x32_bf16(a, b, c, 0, 0, 0);
}

// async global->LDS, 16 B per lane. LDS dest = wave-uniform base + lane*16.
__device__ __forceinline__ void gload_lds16(const u16* g, u16* l) {
    __builtin_amdgcn_global_load_lds(
        (const __attribute__((address_space(1))) void*)g,
        (__attribute__((address_space(3))) void*)l, 16, 0, 0);
}

// #V-columns in [0,x) of the interleaved [q|k|v]x192 layout
__device__ __forceinline__ int Gv(int x) {
    int q = x / 192, rm = x - q * 192;
    int e = rm - 128;
    return q * 64 + (e > 0 ? e : 0);
}

// ---------------- fused prep: cast x (blocks [0,1024)) + transpose W_qkv
// (blocks [1024,4096)) + transpose W_out (blocks [4096,5120)) ----------------
__device__ __forceinline__ void transpose_body(
    const float* __restrict__ in, u16* __restrict__ out,
    int rows, int cols, int bx, int by, float (*tile)[33])
{
    int c0 = bx * 32;
    int r0 = by * 32;
    int tx = threadIdx.x & 31;
    int ty = threadIdx.x >> 5;   // 0..7
#pragma unroll
    for (int i = 0; i < 32; i += 8)
        tile[ty + i][tx] = in[(size_t)(r0 + ty + i) * cols + c0 + tx];
    __syncthreads();
#pragma unroll
    for (int i = 0; i < 32; i += 8)
        out[(size_t)(c0 + ty + i) * rows + r0 + tx] = f2bf(tile[tx][ty + i]);
}

__global__ __launch_bounds__(256) void prep_kernel(
    const float* __restrict__ x, u16* __restrict__ Xb,
    const float* __restrict__ Wqkv, u16* __restrict__ Wqkvt,
    const float* __restrict__ Wout, u16* __restrict__ Woutt)
{
    __shared__ float tile[32][33];
    int b = blockIdx.x;
    if (b < 1024) {
        int n4 = M_TOK * D_MODEL / 4;
        int i = b * 256 + threadIdx.x;
        int stride = 1024 * 256;
        for (; i < n4; i += stride) {
            float4 v = ((const float4*)x)[i];
            ushort4 o;
            o.x = f2bf(v.x); o.y = f2bf(v.y); o.z = f2bf(v.z); o.w = f2bf(v.w);
            ((ushort4*)Xb)[i] = o;
        }
    } else if (b < 1024 + 3072) {
        int bb = b - 1024;
        transpose_body(Wqkv, Wqkvt, 1024, 3072, bb % 96, bb / 96, tile);
    } else {
        int bb = b - 4096;
        transpose_body(Wout, Woutt, 1024, 1024, bb % 32, bb / 32, tile);
    }
}

// ---------------- QKV GEMM: C[4096][3072] = A[4096][1024] * Bt[3072][1024]^T + bias ----------------
// R8 post-mortem: dbuf overlap caused DMA-write/ds_read bank contention (3.3M
// conflicts) and cut blocks/CU 4->3: net regression. R9: serialized staging
// (reads and DMA writes never concurrent) + BN=64 retile -> grid (32,48) =
// 1536 blocks = ~5/CU (LDS 28.6KB). Latency hidden by block-level TLP (m114).
// Bonus: 64-col windows align with the q|k|v 192-period (192=3*64) so each
// block's epilogue is uniformly q, k, or v.
__global__ __launch_bounds__(256) void gemm_qkv_kernel(
    const u16* __restrict__ A, const u16* __restrict__ Bt, const float* __restrict__ bias,
    u16* __restrict__ Qb, u16* __restrict__ Kb, u16* __restrict__ Vp)
{
    __shared__ u16 lA[128 * 32];
    __shared__ u16 lB[64 * 32];
    __shared__ u16 vtile[64 * 132];   // [vloc][sp], stride 132 -> 2-way banks (free)
    int w = threadIdx.x >> 6, l = threadIdx.x & 63;
    int col = l & 15, quad = l >> 4;
    int wm = w >> 1, wn = w & 1;
    int m0 = blockIdx.x * 128;
    int n0 = blockIdx.y * 64;
    int lrow = l >> 2;            // 0..15 within a 16-row slab
    int lcol = (l & 3) * 8;       // 0/8/16/24

    f32x4 acc[4][2] = {};
    for (int k0 = 0; k0 < 1024; k0 += 32) {
        __syncthreads();
#pragma unroll
        for (int i = 0; i < 2; i++) {
            int slab = w * 32 + i * 16;   // A: 8 slabs of 16 rows
            gload_lds16(A + (size_t)(m0 + slab + lrow) * 1024 + k0 + lcol, lA + slab * 32);
        }
        // B: 4 slabs of 16 rows; wave w stages slab w
        gload_lds16(Bt + (size_t)(n0 + w * 16 + lrow) * 1024 + k0 + lcol, lB + (w * 16) * 32);
        __syncthreads();
        bf16x8 af[4], bfr[2];
#pragma unroll
        for (int i = 0; i < 4; i++)
            af[i] = ld_bf8(lA + (wm * 64 + i * 16 + col) * 32 + quad * 8);
#pragma unroll
        for (int j = 0; j < 2; j++)
            bfr[j] = ld_bf8(lB + (wn * 32 + j * 16 + col) * 32 + quad * 8);
#pragma unroll
        for (int i = 0; i < 4; i++)
#pragma unroll
            for (int j = 0; j < 2; j++)
                acc[i][j] = mfma16(af[i], bfr[j], acc[i][j]);
    }

    int s0 = m0 & 2047;
    int bblk = m0 >> 11;
#pragma unroll
    for (int i = 0; i < 4; i++) {
#pragma unroll
        for (int j = 0; j < 2; j++) {
            int cc = n0 + wn * 32 + j * 16 + col;   // 0..3071
            int h = cc / 192;
            int within = cc - h * 192;
            int ww = within >> 6;                   // 0=q 1=k 2=v (uniform per block)
            int d = within & 63;
            int vloc = Gv(cc) - Gv(n0);
            float bv = bias[cc];
#pragma unroll
            for (int r = 0; r < 4; r++) {
                int sloc = wm * 64 + i * 16 + quad * 4 + r;   // 0..127
                int s = s0 + sloc;
                int bh = bblk * NHEAD + h;
                float val = acc[i][j][r] + bv;
                if (ww == 0)      Qb[(size_t)(bh * SEQ + s) * HD + d] = f2bf(val * Q_SCALE);
                else if (ww == 1) Kb[(size_t)(bh * SEQ + s) * HD + d] = f2bf(val);
                else {
                    int sp = (sloc & ~31) | ((sloc & 12) << 1) | (((sloc >> 4) & 1) << 2) | (sloc & 3);
                    vtile[vloc * 132 + sp] = f2bf(val);
                }
            }
        }
    }
    __syncthreads();
    // coalesced V dump: 16B chunks along s' (vcols = 0 or 64 per block)
    int vcols = Gv(n0 + 64) - Gv(n0);
    int gbase = Gv(n0);
    for (int c = threadIdx.x; c < vcols * 16; c += 256) {
        int vloc = c >> 4, gi = c & 15;
        int av = gbase + vloc;
        int h = av >> 6, d = av & 63;
        int bh = bblk * NHEAD + h;
        int4 vv = *(const int4*)(vtile + vloc * 132 + gi * 8);
        *(int4*)(Vp + ((size_t)(bh * HD + d)) * SEQ + s0 + gi * 8) = vv;
    }
}

// ---------------- Flash attention v14: 4-wave blocks, pair-unroll, HW exp2 ----------------
__global__ __launch_bounds__(256, 2) void attn_kernel(
    const u16* __restrict__ Qb, const u16* __restrict__ Kb,
    const u16* __restrict__ Vp, u16* __restrict__ O0,
    u16* __restrict__ O1, float* __restrict__ Lp)
{
    __shared__ u16 kbuf[4][64 * 64];
    __shared__ u16 vbuf[4][64 * 64];
    int wave = threadIdx.x >> 6, lane = threadIdx.x & 63;
    int col = lane & 15, quad = lane >> 4;
    int g = blockIdx.x;
    int xcd = g & 7, slot = g >> 3;        // slot 0..63
    int bh = xcd * 4 + (slot >> 4);        // 0..31 (all work of one bh on one XCD)
    int rem = slot & 15;
    int split = rem >> 3;                  // 0..1
    int qt = rem & 7;                      // 0..7
    int q0 = qt * 256 + wave * 64;
    int kstart = split * 16;               // kt units of 64

    // staging: lane covers row=lane>>3 (of an 8-row slab), 16B group (lane&7),
    // XOR-swizzled source group gs = (lane&7)^(lane>>3)
    int srow = lane >> 3;
    int sgrp = (lane & 7) ^ srow;
    const u16* Kt0 = Kb + (size_t)bh * SEQ * HD;
    const u16* Vt0 = Vp + (size_t)bh * HD * SEQ;
    long soffK = (long)srow * HD + sgrp * 8;
    long soffV = (long)srow * SEQ + sgrp * 8;
    int r0 = wave * 16;                    // this wave stages rows r0..r0+15 of K and V

    // fragment-read lane offsets (LDS elems), swizzle-matched
    int rbase = col * 64;
    int sw0 = ((quad)     ^ (col & 7)) * 8;
    int sw1 = ((quad + 4) ^ (col & 7)) * 8;

    // all-ones bf16 B-fragment for the denominator MFMA
    union { u32 w[4]; int4 i; } onesu;
    onesu.w[0] = onesu.w[1] = onesu.w[2] = onesu.w[3] = 0x3F803F80u;
    bf16x8 ones = as_bf8(onesu.i);

    // persistent zero C-operand
    f32x4 zf = {};

    // Q as B-operand fragments (scale 0.125*log2e pre-folded); one-time load
    bf16x8 aq[4][2];
#pragma unroll
    for (int m = 0; m < 4; m++) {
        const u16* qbase = Qb + ((size_t)bh * SEQ + q0 + m * 16 + col) * HD + quad * 8;
        aq[m][0] = ld_bf8(qbase);
        aq[m][1] = ld_bf8(qbase + 32);
    }

    f32x4 o[4][4] = {};          // [q-frag][d-tile]; lane holds O[q=quad*4+r][d=col..]
    f32x4 ol[4] = {};            // denominator accumulator (row sums)

    // prefetch tiles 0,1 into buffers 0,1
#pragma unroll
    for (int p = 0; p < 2; p++) {
        int kbase = (kstart + p) * 64;
        gload_lds16(Kt0 + (size_t)(kbase + r0) * HD + soffK,      kbuf[p] + r0 * 64);
        gload_lds16(Kt0 + (size_t)(kbase + r0 + 8) * HD + soffK,  kbuf[p] + (r0 + 8) * 64);
        gload_lds16(Vt0 + (size_t)r0 * SEQ + kbase + soffV,       vbuf[p] + r0 * 64);
        gload_lds16(Vt0 + (size_t)(r0 + 8) * SEQ + kbase + soffV, vbuf[p] + (r0 + 8) * 64);
    }

    for (int kt = 0; kt < 16; kt += 2) {
        int pr = (kt >> 1) & 1;            // which buffer pair holds tiles kt,kt+1
        __syncthreads();                   // tiles kt,kt+1 resident; prev pair's reads done
        if (kt + 2 < 16) {
            int npr = pr ^ 1;
#pragma unroll
            for (int p = 0; p < 2; p++) {
                int kbase = (kstart + kt + 2 + p) * 64;
                u16* kd = kbuf[npr * 2 + p];
                u16* vd = vbuf[npr * 2 + p];
                gload_lds16(Kt0 + (size_t)(kbase + r0) * HD + soffK,      kd + r0 * 64);
                gload_lds16(Kt0 + (size_t)(kbase + r0 + 8) * HD + soffK,  kd + (r0 + 8) * 64);
                gload_lds16(Vt0 + (size_t)r0 * SEQ + kbase + soffV,       vd + r0 * 64);
                gload_lds16(Vt0 + (size_t)(r0 + 8) * SEQ + kbase + soffV, vd + (r0 + 8) * 64);
            }
        }
#pragma unroll
        for (int half = 0; half < 2; half++) {
            const u16* kb = kbuf[pr * 2 + half];
            const u16* vb = vbuf[pr * 2 + half];
            bf16x8 kf[4][2];
#pragma unroll
            for (int t = 0; t < 4; t++) {
                kf[t][0] = ld_bf8(kb + t * 1024 + rbase + sw0);
                kf[t][1] = ld_bf8(kb + t * 1024 + rbase + sw1);
            }
            int4 vraw[4][2];
#pragma unroll
            for (int t = 0; t < 4; t++) {
                vraw[t][0] = *(const int4*)(vb + t * 1024 + rbase + sw0);
                vraw[t][1] = *(const int4*)(vb + t * 1024 + rbase + sw1);
            }
            // scores S^T = K*Q^T (mfma cluster), exp2 (VALU), PV+denom (mfma cluster)
#pragma unroll
            for (int m = 0; m < 4; m++) {
                f32x4 sa[4];
                __builtin_amdgcn_s_setprio(1);
#pragma unroll
                for (int t = 0; t < 4; t++) {
                    sa[t] = mfma16(kf[t][0], aq[m][0], zf);
                    sa[t] = mfma16(kf[t][1], aq[m][1], sa[t]);
                }
                __builtin_amdgcn_s_setprio(0);
                int4 pfrag[2];
#pragma unroll
                for (int t = 0; t < 4; t++) {
                    f32x4 p;
#pragma unroll
                    for (int r = 0; r < 4; r++)
                        p[r] = fast_exp2(sa[t][r]);
                    u32 lo = pack_bf(p[0], p[1]);
                    u32 hi = pack_bf(p[2], p[3]);
                    if ((t & 1) == 0) { pfrag[t >> 1].x = (int)lo; pfrag[t >> 1].y = (int)hi; }
                    else              { pfrag[t >> 1].z = (int)lo; pfrag[t >> 1].w = (int)hi; }
                }
                __builtin_amdgcn_s_setprio(1);
#pragma unroll
                for (int t = 0; t < 4; t++)
#pragma unroll
                    for (int h = 0; h < 2; h++)
                        o[m][t] = mfma16(as_bf8(pfrag[h]), as_bf8(vraw[t][h]), o[m][t]);
                ol[m] = mfma16(as_bf8(pfrag[0]), ones, ol[m]);
                ol[m] = mfma16(as_bf8(pfrag[1]), ones, ol[m]);
                __builtin_amdgcn_s_setprio(0);
            }
        }
    }

    // partial epilogue: un-normalized O (bf16) + row denominators (fp32)
    u16* Op = split ? O1 : O0;
#pragma unroll
    for (int m = 0; m < 4; m++) {
#pragma unroll
        for (int r = 0; r < 4; r++) {
            int srow2 = q0 + m * 16 + quad * 4 + r;
            if (col == 0)
                Lp[(size_t)split * 32 * SEQ + (size_t)bh * SEQ + srow2] = ol[m][r];
#pragma unroll
            for (int t = 0; t < 4; t++)
                Op[((size_t)bh * SEQ + srow2) * HD + t * 16 + col] = f2bf(o[m][t][r]);
        }
    }
}

// ---------------- combine: At = (O0 + O1) / (l0 + l1), bf16 out in [b][s][h*64+d] layout ----------------
__global__ __launch_bounds__(256) void combine_kernel(
    const u16* __restrict__ O0, const u16* __restrict__ O1,
    const float* __restrict__ Lp, u16* __restrict__ At)
{
    int i = blockIdx.x * 256 + threadIdx.x;   // 0 .. 32*2048*16-1
    int dg = i & 15;                           // 4-d group
    int q = (i >> 4) & 2047;
    int bh = i >> 15;                          // 0..31
    size_t ob = ((size_t)bh * SEQ + q) * HD + dg * 4;
    ushort4 a = *(const ushort4*)(O0 + ob);
    ushort4 b = *(const ushort4*)(O1 + ob);
    float l = Lp[(size_t)bh * SEQ + q] + Lp[(size_t)32 * SEQ + (size_t)bh * SEQ + q];
    float inv = 1.f / l;
    int bb = bh >> 4, h = bh & 15;
    ushort4 o;
    o.x = f2bf((bf2f(a.x) + bf2f(b.x)) * inv);
    o.y = f2bf((bf2f(a.y) + bf2f(b.y)) * inv);
    o.z = f2bf((bf2f(a.z) + bf2f(b.z)) * inv);
    o.w = f2bf((bf2f(a.w) + bf2f(b.w)) * inv);
    *(ushort4*)(At + ((size_t)(bb * SEQ + q)) * D_MODEL + h * 64 + dg * 4) = o;
}

// ---------------- out proj: out[4096][1024] = A[4096][1024] * Bt[1024][1024]^T + bias ----------------
// R8 accounting: grid (32,8) = 256 blocks = 1 block/CU -> zero inter-block
// latency hiding. R9: BN=64 -> grid (32,16) = 512 blocks, LDS 12KB -> multiple
// blocks/CU. Serialized staging (no DMA/read overlap).
__global__ __launch_bounds__(256) void gemm_out_kernel(
    const u16* __restrict__ A, const u16* __restrict__ Bt, const float* __restrict__ bias,
    float* __restrict__ out)
{
    __shared__ u16 lA[128 * 32];
    __shared__ u16 lB[64 * 32];
    int w = threadIdx.x >> 6, l = threadIdx.x & 63;
    int col = l & 15, quad = l >> 4;
    int wm = w >> 1, wn = w & 1;
    int m0 = blockIdx.x * 128;
    int n0 = blockIdx.y * 64;
    int lrow = l >> 2;
    int lcol = (l & 3) * 8;

    f32x4 acc[4][2] = {};
    for (int k0 = 0; k0 < 1024; k0 += 32) {
        __syncthreads();
#pragma unroll
        for (int i = 0; i < 2; i++) {
            int slab = w * 32 + i * 16;
            gload_lds16(A + (size_t)(m0 + slab + lrow) * 1024 + k0 + lcol, lA + slab * 32);
        }
        gload_lds16(Bt + (size_t)(n0 + w * 16 + lrow) * 1024 + k0 + lcol, lB + (w * 16) * 32);
        __syncthreads();
        bf16x8 af[4], bfr[2];
#pragma unroll
        for (int i = 0; i < 4; i++)
            af[i] = ld_bf8(lA + (wm * 64 + i * 16 + col) * 32 + quad * 8);
#pragma unroll
        for (int j = 0; j < 2; j++)
            bfr[j] = ld_bf8(lB + (wn * 32 + j * 16 + col) * 32 + quad * 8);
#pragma unroll
        for (int i = 0; i < 4; i++)
#pragma unroll
            for (int j = 0; j < 2; j++)
                acc[i][j] = mfma16(af[i], bfr[j], acc[i][j]);
    }

#pragma unroll
    for (int i = 0; i < 4; i++) {
#pragma unroll
        for (int j = 0; j < 2; j++) {
            int cc = n0 + wn * 32 + j * 16 + col;
            float bv = bias[cc];
#pragma unroll
            for (int r = 0; r < 4; r++) {
                int row = m0 + wm * 64 + i * 16 + quad * 4 + r;
                out[(size_t)row * D_MODEL + cc] = acc[i][j][r] + bv;
            }
        }
    }
}

extern "C" void kernel_launch(void* const* d_in, const int* in_sizes, int n_in,
                              void* d_out, int out_size, void* d_ws, size_t ws_size,
                              hipStream_t stream) {
    const float* x     = (const float*)d_in[0];
    const float* W_qkv = (const float*)d_in[1];
    const float* b_qkv = (const float*)d_in[2];
    const float* W_out = (const float*)d_in[3];
    const float* b_out = (const float*)d_in[4];
    float* out = (float*)d_out;

    // Workspace overlays (<=48 MB):
    //   [0,8)   Xb (cast input)   -> after gemm_qkv: O0 partial
    //   [8,16)  Wqkvt             -> after gemm_qkv: O1 partial
    //   [16,24) Qb                -> after attn: At (combine output)
    //   [24,32) Kb
    //   [32,40) Vp (permuted V)
    //   [40,40.5) Lp (fp32 split denominators)
    //   [41,43) Woutt (bf16 W_out^T, written by prep, read by gemm_out)
    char* ws = (char*)d_ws;
    u16* Xb    = (u16*)(ws);
    u16* Wqkvt = (u16*)(ws + (8ull << 20));
    u16* Qb    = (u16*)(ws + (16ull << 20));
    u16* Kb    = (u16*)(ws + (24ull << 20));
    u16* Vp    = (u16*)(ws + (32ull << 20));
    u16* O0    = (u16*)(ws);
    u16* O1    = (u16*)(ws + (8ull << 20));
    float* Lp  = (float*)(ws + (40ull << 20));
    u16* At    = (u16*)(ws + (16ull << 20));
    u16* Woutt = (u16*)(ws + (41ull << 20));

    prep_kernel<<<dim3(5120), 256, 0, stream>>>(x, Xb, W_qkv, Wqkvt, W_out, Woutt);
    gemm_qkv_kernel<<<dim3(32, 48), 256, 0, stream>>>(Xb, Wqkvt, b_qkv, Qb, Kb, Vp);
    attn_kernel<<<dim3(512), 256, 0, stream>>>(Qb, Kb, Vp, O0, O1, Lp);
    combine_kernel<<<dim3(BATCH * NHEAD * SEQ * (HD / 4) / 256), 256, 0, stream>>>(O0, O1, Lp, At);
    gemm_out_kernel<<<dim3(32, 16), 256, 0, stream>>>(At, Woutt, b_out, out);
}

// Round 10
// 181.355 us; speedup vs baseline: 1.0489x; 1.0489x over previous
//
#include <hip/hip_runtime.h>
#include <cmath>

typedef unsigned short u16;
typedef unsigned int u32;
typedef __bf16 bf16x8 __attribute__((ext_vector_type(8)));
typedef float f32x4 __attribute__((ext_vector_type(4)));

#define D_MODEL 1024
#define NHEAD 16
#define HD 64
#define SEQ 2048
#define BATCH 2
#define M_TOK 4096      // BATCH*SEQ
#define N_QKV 3072

// Q epilogue scale: 0.125 (1/sqrt(64)) * log2(e), folded so softmax is a bare exp2
#define Q_SCALE 0.18033688011112042f

// float -> bf16 round-to-nearest-even (matches HW cvt)
__device__ __forceinline__ u16 f2bf(float f) {
    u32 u = __float_as_uint(f);
    u32 r = (u + 0x7fffu + ((u >> 16) & 1u)) >> 16;
    return (u16)r;
}

__device__ __forceinline__ float bf2f(u16 v) {
    return __uint_as_float(((u32)v) << 16);
}

// HW exp2: single v_exp_f32 (R6->R7 win: -17us, OCML expansion removed)
__device__ __forceinline__ float fast_exp2(float x) {
#if __has_builtin(__builtin_amdgcn_exp2f)
    return __builtin_amdgcn_exp2f(x);
#else
    return __exp2f(x);
#endif
}

// pack two fp32 -> two bf16 in one b32 (a in low half)
__device__ __forceinline__ u32 pack_bf(float a, float b) {
#if __has_builtin(__builtin_amdgcn_cvt_pk_bf16_f32)
    typedef __bf16 bf16x2_t __attribute__((ext_vector_type(2)));
    union { bf16x2_t v; u32 u; } c;
    c.v = __builtin_amdgcn_cvt_pk_bf16_f32(a, b);
    return c.u;
#else
    u32 ua = __float_as_uint(a) + 0x8000u;
    u32 ub = __float_as_uint(b) + 0x8000u;
    return __builtin_amdgcn_perm(ub, ua, 0x07060302u);
#endif
}

__device__ __forceinline__ bf16x8 ld_bf8(const u16* p) {
    return *(const bf16x8*)p;
}

__device__ __forceinline__ bf16x8 as_bf8(int4 v) {
    union { int4 i; bf16x8 b; } u; u.i = v; return u.b;
}

__device__ __forceinline__ f32x4 mfma16(bf16x8 a, bf16x8 b, f32x4 c) {
    return __builtin_amdgcn_mfma_f32_16x16x32_bf16(a, b, c, 0, 0, 0);
}

// async global->LDS, 16 B per lane. LDS dest = wave-uniform base + lane*16.
__device__ __forceinline__ void gload_lds16(const u16* g, u16* l) {
    __builtin_amdgcn_global_load_lds(
        (const __attribute__((address_space(1))) void*)g,
        (__attribute__((address_space(3))) void*)l, 16, 0, 0);
}

// #V-columns in [0,x) of the interleaved [q|k|v]x192 layout
__device__ __forceinline__ int Gv(int x) {
    int q = x / 192, rm = x - q * 192;
    int e = rm - 128;
    return q * 64 + (e > 0 ? e : 0);
}

// ---------------- fused prep: cast x (blocks [0,1024)) + transpose W_qkv
// (blocks [1024,4096)) + transpose W_out (blocks [4096,5120)) ----------------
__device__ __forceinline__ void transpose_body(
    const float* __restrict__ in, u16* __restrict__ out,
    int rows, int cols, int bx, int by, float (*tile)[33])
{
    int c0 = bx * 32;
    int r0 = by * 32;
    int tx = threadIdx.x & 31;
    int ty = threadIdx.x >> 5;   // 0..7
#pragma unroll
    for (int i = 0; i < 32; i += 8)
        tile[ty + i][tx] = in[(size_t)(r0 + ty + i) * cols + c0 + tx];
    __syncthreads();
#pragma unroll
    for (int i = 0; i < 32; i += 8)
        out[(size_t)(c0 + ty + i) * rows + r0 + tx] = f2bf(tile[tx][ty + i]);
}

__global__ __launch_bounds__(256) void prep_kernel(
    const float* __restrict__ x, u16* __restrict__ Xb,
    const float* __restrict__ Wqkv, u16* __restrict__ Wqkvt,
    const float* __restrict__ Wout, u16* __restrict__ Woutt)
{
    __shared__ float tile[32][33];
    int b = blockIdx.x;
    if (b < 1024) {
        int n4 = M_TOK * D_MODEL / 4;
        int i = b * 256 + threadIdx.x;
        int stride = 1024 * 256;
        for (; i < n4; i += stride) {
            float4 v = ((const float4*)x)[i];
            ushort4 o;
            o.x = f2bf(v.x); o.y = f2bf(v.y); o.z = f2bf(v.z); o.w = f2bf(v.w);
            ((ushort4*)Xb)[i] = o;
        }
    } else if (b < 1024 + 3072) {
        int bb = b - 1024;
        transpose_body(Wqkv, Wqkvt, 1024, 3072, bb % 96, bb / 96, tile);
    } else {
        int bb = b - 4096;
        transpose_body(Wout, Woutt, 1024, 1024, bb % 32, bb / 32, tile);
    }
}

// ---------------- QKV GEMM: C[4096][3072] = A[4096][1024] * Bt[3072][1024]^T + bias ----------------
// R9 diagnosis: fragment ds_read_b128 on the [row][32] layout is an 8-way
// bank conflict (bank-group (4*col+quad)%8 takes 2 values across 16 lanes) --
// present since R1, 3-5M conflict cycles. Fix (rule #21 both-sides): LDS dest
// stays linear for global_load_lds; the GLOBAL source group is pre-swizzled
// (lcol = ((l&3)^((l>>3)&3))*8) so slot (row,gs) holds logical group
// gs^((row>>1)&3); fragment reads use gsw = (quad^((col>>1)&3))*8. Bank-group
// becomes 4*(col&1)+quad^((col>>1)&3): all 8 covered, 2-way = free.
__global__ __launch_bounds__(256) void gemm_qkv_kernel(
    const u16* __restrict__ A, const u16* __restrict__ Bt, const float* __restrict__ bias,
    u16* __restrict__ Qb, u16* __restrict__ Kb, u16* __restrict__ Vp)
{
    __shared__ u16 lA[128 * 32];
    __shared__ u16 lB[128 * 32];
    __shared__ u16 vtile[64 * 132];   // [vloc][sp], stride 132 -> 2-way banks (free)
    int w = threadIdx.x >> 6, l = threadIdx.x & 63;
    int col = l & 15, quad = l >> 4;
    int wm = w >> 1, wn = w & 1;
    int m0 = blockIdx.x * 128;
    int n0 = blockIdx.y * 128;
    int lrow = l >> 2;                              // 0..15 within a 16-row slab
    int lcol = (((l & 3) ^ ((l >> 3) & 3))) * 8;    // pre-swizzled source group
    int gsw = (quad ^ ((col >> 1) & 3)) * 8;        // swizzle-matched read offset

    f32x4 acc[4][4] = {};
    for (int k0 = 0; k0 < 1024; k0 += 32) {
        __syncthreads();
#pragma unroll
        for (int i = 0; i < 2; i++) {
            int slab = w * 32 + i * 16;   // 16 rows per wave-issue
            gload_lds16(A  + (size_t)(m0 + slab + lrow) * 1024 + k0 + lcol, lA + slab * 32);
            gload_lds16(Bt + (size_t)(n0 + slab + lrow) * 1024 + k0 + lcol, lB + slab * 32);
        }
        __syncthreads();
        bf16x8 af[4], bfr[4];
#pragma unroll
        for (int i = 0; i < 4; i++)
            af[i] = ld_bf8(lA + (wm * 64 + i * 16 + col) * 32 + gsw);
#pragma unroll
        for (int j = 0; j < 4; j++)
            bfr[j] = ld_bf8(lB + (wn * 64 + j * 16 + col) * 32 + gsw);
#pragma unroll
        for (int i = 0; i < 4; i++)
#pragma unroll
            for (int j = 0; j < 4; j++)
                acc[i][j] = mfma16(af[i], bfr[j], acc[i][j]);
    }

    int s0 = m0 & 2047;
    int bblk = m0 >> 11;
#pragma unroll
    for (int i = 0; i < 4; i++) {
#pragma unroll
        for (int j = 0; j < 4; j++) {
            int cc = n0 + wn * 64 + j * 16 + col;   // 0..3071
            int h = cc / 192;
            int within = cc - h * 192;
            int ww = within >> 6;                   // 0=q 1=k 2=v
            int d = within & 63;
            int vloc = Gv(cc) - Gv(n0);
            float bv = bias[cc];
#pragma unroll
            for (int r = 0; r < 4; r++) {
                int sloc = wm * 64 + i * 16 + quad * 4 + r;   // 0..127
                int s = s0 + sloc;
                int bh = bblk * NHEAD + h;
                float val = acc[i][j][r] + bv;
                if (ww == 0)      Qb[(size_t)(bh * SEQ + s) * HD + d] = f2bf(val * Q_SCALE);
                else if (ww == 1) Kb[(size_t)(bh * SEQ + s) * HD + d] = f2bf(val);
                else {
                    int sp = (sloc & ~31) | ((sloc & 12) << 1) | (((sloc >> 4) & 1) << 2) | (sloc & 3);
                    vtile[vloc * 132 + sp] = f2bf(val);
                }
            }
        }
    }
    __syncthreads();
    // coalesced V dump: 16B chunks along s'
    int vcols = Gv(n0 + 128) - Gv(n0);
    int gbase = Gv(n0);
    for (int c = threadIdx.x; c < vcols * 16; c += 256) {
        int vloc = c >> 4, gi = c & 15;
        int av = gbase + vloc;
        int h = av >> 6, d = av & 63;
        int bh = bblk * NHEAD + h;
        int4 vv = *(const int4*)(vtile + vloc * 132 + gi * 8);
        *(int4*)(Vp + ((size_t)(bh * HD + d)) * SEQ + s0 + gi * 8) = vv;
    }
}

// ---------------- Flash attention v14: 4-wave blocks, pair-unroll, HW exp2 ----------------
__global__ __launch_bounds__(256, 2) void attn_kernel(
    const u16* __restrict__ Qb, const u16* __restrict__ Kb,
    const u16* __restrict__ Vp, u16* __restrict__ O0,
    u16* __restrict__ O1, float* __restrict__ Lp)
{
    __shared__ u16 kbuf[4][64 * 64];
    __shared__ u16 vbuf[4][64 * 64];
    int wave = threadIdx.x >> 6, lane = threadIdx.x & 63;
    int col = lane & 15, quad = lane >> 4;
    int g = blockIdx.x;
    int xcd = g & 7, slot = g >> 3;        // slot 0..63
    int bh = xcd * 4 + (slot >> 4);        // 0..31 (all work of one bh on one XCD)
    int rem = slot & 15;
    int split = rem >> 3;                  // 0..1
    int qt = rem & 7;                      // 0..7
    int q0 = qt * 256 + wave * 64;
    int kstart = split * 16;               // kt units of 64

    // staging: lane covers row=lane>>3 (of an 8-row slab), 16B group (lane&7),
    // XOR-swizzled source group gs = (lane&7)^(lane>>3)
    int srow = lane >> 3;
    int sgrp = (lane & 7) ^ srow;
    const u16* Kt0 = Kb + (size_t)bh * SEQ * HD;
    const u16* Vt0 = Vp + (size_t)bh * HD * SEQ;
    long soffK = (long)srow * HD + sgrp * 8;
    long soffV = (long)srow * SEQ + sgrp * 8;
    int r0 = wave * 16;                    // this wave stages rows r0..r0+15 of K and V

    // fragment-read lane offsets (LDS elems), swizzle-matched
    int rbase = col * 64;
    int sw0 = ((quad)     ^ (col & 7)) * 8;
    int sw1 = ((quad + 4) ^ (col & 7)) * 8;

    // all-ones bf16 B-fragment for the denominator MFMA
    union { u32 w[4]; int4 i; } onesu;
    onesu.w[0] = onesu.w[1] = onesu.w[2] = onesu.w[3] = 0x3F803F80u;
    bf16x8 ones = as_bf8(onesu.i);

    // persistent zero C-operand
    f32x4 zf = {};

    // Q as B-operand fragments (scale 0.125*log2e pre-folded); one-time load
    bf16x8 aq[4][2];
#pragma unroll
    for (int m = 0; m < 4; m++) {
        const u16* qbase = Qb + ((size_t)bh * SEQ + q0 + m * 16 + col) * HD + quad * 8;
        aq[m][0] = ld_bf8(qbase);
        aq[m][1] = ld_bf8(qbase + 32);
    }

    f32x4 o[4][4] = {};          // [q-frag][d-tile]; lane holds O[q=quad*4+r][d=col..]
    f32x4 ol[4] = {};            // denominator accumulator (row sums)

    // prefetch tiles 0,1 into buffers 0,1
#pragma unroll
    for (int p = 0; p < 2; p++) {
        int kbase = (kstart + p) * 64;
        gload_lds16(Kt0 + (size_t)(kbase + r0) * HD + soffK,      kbuf[p] + r0 * 64);
        gload_lds16(Kt0 + (size_t)(kbase + r0 + 8) * HD + soffK,  kbuf[p] + (r0 + 8) * 64);
        gload_lds16(Vt0 + (size_t)r0 * SEQ + kbase + soffV,       vbuf[p] + r0 * 64);
        gload_lds16(Vt0 + (size_t)(r0 + 8) * SEQ + kbase + soffV, vbuf[p] + (r0 + 8) * 64);
    }

    for (int kt = 0; kt < 16; kt += 2) {
        int pr = (kt >> 1) & 1;            // which buffer pair holds tiles kt,kt+1
        __syncthreads();                   // tiles kt,kt+1 resident; prev pair's reads done
        if (kt + 2 < 16) {
            int npr = pr ^ 1;
#pragma unroll
            for (int p = 0; p < 2; p++) {
                int kbase = (kstart + kt + 2 + p) * 64;
                u16* kd = kbuf[npr * 2 + p];
                u16* vd = vbuf[npr * 2 + p];
                gload_lds16(Kt0 + (size_t)(kbase + r0) * HD + soffK,      kd + r0 * 64);
                gload_lds16(Kt0 + (size_t)(kbase + r0 + 8) * HD + soffK,  kd + (r0 + 8) * 64);
                gload_lds16(Vt0 + (size_t)r0 * SEQ + kbase + soffV,       vd + r0 * 64);
                gload_lds16(Vt0 + (size_t)(r0 + 8) * SEQ + kbase + soffV, vd + (r0 + 8) * 64);
            }
        }
#pragma unroll
        for (int half = 0; half < 2; half++) {
            const u16* kb = kbuf[pr * 2 + half];
            const u16* vb = vbuf[pr * 2 + half];
            bf16x8 kf[4][2];
#pragma unroll
            for (int t = 0; t < 4; t++) {
                kf[t][0] = ld_bf8(kb + t * 1024 + rbase + sw0);
                kf[t][1] = ld_bf8(kb + t * 1024 + rbase + sw1);
            }
            int4 vraw[4][2];
#pragma unroll
            for (int t = 0; t < 4; t++) {
                vraw[t][0] = *(const int4*)(vb + t * 1024 + rbase + sw0);
                vraw[t][1] = *(const int4*)(vb + t * 1024 + rbase + sw1);
            }
            // scores S^T = K*Q^T (mfma cluster), exp2 (VALU), PV+denom (mfma cluster)
#pragma unroll
            for (int m = 0; m < 4; m++) {
                f32x4 sa[4];
                __builtin_amdgcn_s_setprio(1);
#pragma unroll
                for (int t = 0; t < 4; t++) {
                    sa[t] = mfma16(kf[t][0], aq[m][0], zf);
                    sa[t] = mfma16(kf[t][1], aq[m][1], sa[t]);
                }
                __builtin_amdgcn_s_setprio(0);
                int4 pfrag[2];
#pragma unroll
                for (int t = 0; t < 4; t++) {
                    f32x4 p;
#pragma unroll
                    for (int r = 0; r < 4; r++)
                        p[r] = fast_exp2(sa[t][r]);
                    u32 lo = pack_bf(p[0], p[1]);
                    u32 hi = pack_bf(p[2], p[3]);
                    if ((t & 1) == 0) { pfrag[t >> 1].x = (int)lo; pfrag[t >> 1].y = (int)hi; }
                    else              { pfrag[t >> 1].z = (int)lo; pfrag[t >> 1].w = (int)hi; }
                }
                __builtin_amdgcn_s_setprio(1);
#pragma unroll
                for (int t = 0; t < 4; t++)
#pragma unroll
                    for (int h = 0; h < 2; h++)
                        o[m][t] = mfma16(as_bf8(pfrag[h]), as_bf8(vraw[t][h]), o[m][t]);
                ol[m] = mfma16(as_bf8(pfrag[0]), ones, ol[m]);
                ol[m] = mfma16(as_bf8(pfrag[1]), ones, ol[m]);
                __builtin_amdgcn_s_setprio(0);
            }
        }
    }

    // partial epilogue: un-normalized O (bf16) + row denominators (fp32)
    u16* Op = split ? O1 : O0;
#pragma unroll
    for (int m = 0; m < 4; m++) {
#pragma unroll
        for (int r = 0; r < 4; r++) {
            int srow2 = q0 + m * 16 + quad * 4 + r;
            if (col == 0)
                Lp[(size_t)split * 32 * SEQ + (size_t)bh * SEQ + srow2] = ol[m][r];
#pragma unroll
            for (int t = 0; t < 4; t++)
                Op[((size_t)bh * SEQ + srow2) * HD + t * 16 + col] = f2bf(o[m][t][r]);
        }
    }
}

// ---------------- combine: At = (O0 + O1) / (l0 + l1), bf16 out in [b][s][h*64+d] layout ----------------
__global__ __launch_bounds__(256) void combine_kernel(
    const u16* __restrict__ O0, const u16* __restrict__ O1,
    const float* __restrict__ Lp, u16* __restrict__ At)
{
    int i = blockIdx.x * 256 + threadIdx.x;   // 0 .. 32*2048*16-1
    int dg = i & 15;                           // 4-d group
    int q = (i >> 4) & 2047;
    int bh = i >> 15;                          // 0..31
    size_t ob = ((size_t)bh * SEQ + q) * HD + dg * 4;
    ushort4 a = *(const ushort4*)(O0 + ob);
    ushort4 b = *(const ushort4*)(O1 + ob);
    float l = Lp[(size_t)bh * SEQ + q] + Lp[(size_t)32 * SEQ + (size_t)bh * SEQ + q];
    float inv = 1.f / l;
    int bb = bh >> 4, h = bh & 15;
    ushort4 o;
    o.x = f2bf((bf2f(a.x) + bf2f(b.x)) * inv);
    o.y = f2bf((bf2f(a.y) + bf2f(b.y)) * inv);
    o.z = f2bf((bf2f(a.z) + bf2f(b.z)) * inv);
    o.w = f2bf((bf2f(a.w) + bf2f(b.w)) * inv);
    *(ushort4*)(At + ((size_t)(bb * SEQ + q)) * D_MODEL + h * 64 + dg * 4) = o;
}

// ---------------- out proj: out[4096][1024] = A[4096][1024] * Bt[1024][1024]^T + bias ----------------
// Same bank-conflict fix as gemm_qkv (swizzled source group + swizzled reads).
__global__ __launch_bounds__(256) void gemm_out_kernel(
    const u16* __restrict__ A, const u16* __restrict__ Bt, const float* __restrict__ bias,
    float* __restrict__ out)
{
    __shared__ u16 lA[128 * 32];
    __shared__ u16 lB[128 * 32];
    int w = threadIdx.x >> 6, l = threadIdx.x & 63;
    int col = l & 15, quad = l >> 4;
    int wm = w >> 1, wn = w & 1;
    int m0 = blockIdx.x * 128;
    int n0 = blockIdx.y * 128;
    int lrow = l >> 2;
    int lcol = (((l & 3) ^ ((l >> 3) & 3))) * 8;
    int gsw = (quad ^ ((col >> 1) & 3)) * 8;

    f32x4 acc[4][4] = {};
    for (int k0 = 0; k0 < 1024; k0 += 32) {
        __syncthreads();
#pragma unroll
        for (int i = 0; i < 2; i++) {
            int slab = w * 32 + i * 16;
            gload_lds16(A  + (size_t)(m0 + slab + lrow) * 1024 + k0 + lcol, lA + slab * 32);
            gload_lds16(Bt + (size_t)(n0 + slab + lrow) * 1024 + k0 + lcol, lB + slab * 32);
        }
        __syncthreads();
        bf16x8 af[4], bfr[4];
#pragma unroll
        for (int i = 0; i < 4; i++)
            af[i] = ld_bf8(lA + (wm * 64 + i * 16 + col) * 32 + gsw);
#pragma unroll
        for (int j = 0; j < 4; j++)
            bfr[j] = ld_bf8(lB + (wn * 64 + j * 16 + col) * 32 + gsw);
#pragma unroll
        for (int i = 0; i < 4; i++)
#pragma unroll
            for (int j = 0; j < 4; j++)
                acc[i][j] = mfma16(af[i], bfr[j], acc[i][j]);
    }

#pragma unroll
    for (int i = 0; i < 4; i++) {
#pragma unroll
        for (int j = 0; j < 4; j++) {
            int cc = n0 + wn * 64 + j * 16 + col;
            float bv = bias[cc];
#pragma unroll
            for (int r = 0; r < 4; r++) {
                int row = m0 + wm * 64 + i * 16 + quad * 4 + r;
                out[(size_t)row * D_MODEL + cc] = acc[i][j][r] + bv;
            }
        }
    }
}

extern "C" void kernel_launch(void* const* d_in, const int* in_sizes, int n_in,
                              void* d_out, int out_size, void* d_ws, size_t ws_size,
                              hipStream_t stream) {
    const float* x     = (const float*)d_in[0];
    const float* W_qkv = (const float*)d_in[1];
    const float* b_qkv = (const float*)d_in[2];
    const float* W_out = (const float*)d_in[3];
    const float* b_out = (const float*)d_in[4];
    float* out = (float*)d_out;

    // Workspace overlays (<=48 MB):
    //   [0,8)   Xb (cast input)   -> after gemm_qkv: O0 partial
    //   [8,16)  Wqkvt             -> after gemm_qkv: O1 partial
    //   [16,24) Qb                -> after attn: At (combine output)
    //   [24,32) Kb
    //   [32,40) Vp (permuted V)
    //   [40,40.5) Lp (fp32 split denominators)
    //   [41,43) Woutt (bf16 W_out^T, written by prep, read by gemm_out)
    char* ws = (char*)d_ws;
    u16* Xb    = (u16*)(ws);
    u16* Wqkvt = (u16*)(ws + (8ull << 20));
    u16* Qb    = (u16*)(ws + (16ull << 20));
    u16* Kb    = (u16*)(ws + (24ull << 20));
    u16* Vp    = (u16*)(ws + (32ull << 20));
    u16* O0    = (u16*)(ws);
    u16* O1    = (u16*)(ws + (8ull << 20));
    float* Lp  = (float*)(ws + (40ull << 20));
    u16* At    = (u16*)(ws + (16ull << 20));
    u16* Woutt = (u16*)(ws + (41ull << 20));

    prep_kernel<<<dim3(5120), 256, 0, stream>>>(x, Xb, W_qkv, Wqkvt, W_out, Woutt);
    gemm_qkv_kernel<<<dim3(32, 24), 256, 0, stream>>>(Xb, Wqkvt, b_qkv, Qb, Kb, Vp);
    attn_kernel<<<dim3(512), 256, 0, stream>>>(Qb, Kb, Vp, O0, O1, Lp);
    combine_kernel<<<dim3(BATCH * NHEAD * SEQ * (HD / 4) / 256), 256, 0, stream>>>(O0, O1, Lp, At);
    gemm_out_kernel<<<dim3(32, 8), 256, 0, stream>>>(At, Woutt, b_out, out);
}